// Round 1
// baseline (9067.216 us; speedup 1.0000x reference)
//
#include <hip/hip_runtime.h>

typedef unsigned short u16;
typedef __bf16 bf16_t;
typedef bf16_t bf16x8 __attribute__((ext_vector_type(8)));
typedef u16 u16x8 __attribute__((ext_vector_type(8)));
typedef float f32x4 __attribute__((ext_vector_type(4)));

__device__ __forceinline__ u16 f2bf(float f) {
    unsigned u = __builtin_bit_cast(unsigned, f);
    u += 0x7fffu + ((u >> 16) & 1u);   // RNE
    return (u16)(u >> 16);
}
__device__ __forceinline__ float bf2f(u16 h) {
    unsigned u = ((unsigned)h) << 16;
    return __builtin_bit_cast(float, u);
}
__device__ __forceinline__ float fast_tanh(float x) {
    x = fminf(fmaxf(x, -20.f), 20.f);
    float e = __expf(2.f * x);
    return (e - 1.f) * __builtin_amdgcn_rcpf(e + 1.f);
}

__device__ __forceinline__ void gload_lds16(const void* g, void* l) {
    __builtin_amdgcn_global_load_lds((__attribute__((address_space(1))) void*)(g),
                                     (__attribute__((address_space(3))) void*)(l),
                                     16, 0, 0);
}

// ---------------- conversion kernels ----------------

__global__ void cvt_bf16(const float* __restrict__ src, u16* __restrict__ dst, int n4) {
    int i = blockIdx.x * blockDim.x + threadIdx.x;
    if (i < n4) {
        float4 v = ((const float4*)src)[i];
        ushort4 o;
        o.x = f2bf(v.x); o.y = f2bf(v.y); o.z = f2bf(v.z); o.w = f2bf(v.w);
        ((ushort4*)dst)[i] = o;
    }
}

// W: R x C fp32  ->  WT: C x R bf16
__global__ void transpose_cvt(const float* __restrict__ W, u16* __restrict__ WT, int R, int C) {
    __shared__ float tile[32][33];
    int c0 = blockIdx.x * 32, r0 = blockIdx.y * 32;
    int tx = threadIdx.x & 31, ty = threadIdx.x >> 5;  // 32x8
#pragma unroll
    for (int i = 0; i < 32; i += 8)
        tile[ty + i][tx] = W[(size_t)(r0 + ty + i) * C + (c0 + tx)];
    __syncthreads();
#pragma unroll
    for (int i = 0; i < 32; i += 8)
        WT[(size_t)(c0 + ty + i) * R + (r0 + tx)] = f2bf(tile[tx][ty + i]);
}

// ---------------- fused NT GEMM ----------------
// C[m,n] = sum_k A[m,k] * B[n,k];  A: M x K bf16 (lda=K), B: N x K bf16 (ldb=K)
// M = 4096 fixed by grid.y*128. ldc = N.
// mode 0 (FWD):  v = tanh(C + bias[n]);               write outf, outbf
// mode 1 (ERR):  v = rsrc - tanh(C);                  write outbf        (+ 0.5*v^2 if accum)
// mode 2 (UPD):  v = rsrc + 0.1*(C - bf2f(esub));     write outf, outbf
// mode 3 (UPD3): v = 0.9*rsrc + 0.1*C;                write outf, outbf  (+ 0.5*v^2 if accum)

#define BM 128
#define BN 128
#define BK 32

__global__ __launch_bounds__(256) void pc_gemm_nt(
    const u16* __restrict__ A, const u16* __restrict__ B,
    int K, int N,
    const float* __restrict__ rsrc, const float* __restrict__ bias,
    const u16* __restrict__ esub,
    float* __restrict__ outf, u16* __restrict__ outbf,
    float* __restrict__ errAcc,
    int mode, int accum)
{
    __shared__ u16 As[4096];   // [kb 0..3][m 0..127][8]
    __shared__ u16 Bs[4096];   // [kb 0..3][n 0..127][8]
    __shared__ float red[4];

    const int tid  = threadIdx.x;
    const int wave = tid >> 6, lane = tid & 63;
    const int q    = lane >> 4, ln = lane & 15;
    const int wrow = (wave >> 1) * 64, wcol = (wave & 1) * 64;

    const int rowA0 = blockIdx.y * BM;
    const int rowB0 = blockIdx.x * BN;

    // staging sources for this wave: kblock = wave, rows [0,64) and [64,128)
    const u16* gA0 = A + (size_t)(rowA0 + lane) * K + wave * 8;
    const u16* gA1 = A + (size_t)(rowA0 + 64 + lane) * K + wave * 8;
    const u16* gB0 = B + (size_t)(rowB0 + lane) * K + wave * 8;
    const u16* gB1 = B + (size_t)(rowB0 + 64 + lane) * K + wave * 8;
    u16* lA0 = &As[wave * 1024];
    u16* lA1 = &As[wave * 1024 + 512];
    u16* lB0 = &Bs[wave * 1024];
    u16* lB1 = &Bs[wave * 1024 + 512];

    f32x4 acc[4][4];
#pragma unroll
    for (int i = 0; i < 4; ++i)
#pragma unroll
        for (int j = 0; j < 4; ++j)
            acc[i][j] = (f32x4){0.f, 0.f, 0.f, 0.f};

    for (int k0 = 0; k0 < K; k0 += BK) {
        gload_lds16(gA0 + k0, lA0);
        gload_lds16(gA1 + k0, lA1);
        gload_lds16(gB0 + k0, lB0);
        gload_lds16(gB1 + k0, lB1);
        __syncthreads();

        bf16x8 a[4], b[4];
#pragma unroll
        for (int mt = 0; mt < 4; ++mt)
            a[mt] = __builtin_bit_cast(bf16x8,
                *(const u16x8*)&As[q * 1024 + (wrow + mt * 16 + ln) * 8]);
#pragma unroll
        for (int nt = 0; nt < 4; ++nt)
            b[nt] = __builtin_bit_cast(bf16x8,
                *(const u16x8*)&Bs[q * 1024 + (wcol + nt * 16 + ln) * 8]);
#pragma unroll
        for (int mt = 0; mt < 4; ++mt)
#pragma unroll
            for (int nt = 0; nt < 4; ++nt)
                acc[mt][nt] = __builtin_amdgcn_mfma_f32_16x16x32_bf16(
                    a[mt], b[nt], acc[mt][nt], 0, 0, 0);
        __syncthreads();
    }

    // epilogue: C/D layout col = lane&15 (n), row = q*4 + reg (m)
    float lsum = 0.f;
    const int ncol0 = rowB0 + wcol + ln;
#pragma unroll
    for (int mt = 0; mt < 4; ++mt) {
#pragma unroll
        for (int r = 0; r < 4; ++r) {
            int m = rowA0 + wrow + mt * 16 + q * 4 + r;
            size_t off = (size_t)m * N;
#pragma unroll
            for (int nt = 0; nt < 4; ++nt) {
                int n = ncol0 + nt * 16;
                size_t idx = off + n;
                float c = acc[mt][nt][r];
                if (mode == 0) {
                    float v = fast_tanh(c + bias[n]);
                    outf[idx] = v; outbf[idx] = f2bf(v);
                } else if (mode == 1) {
                    float v = rsrc[idx] - fast_tanh(c);
                    outbf[idx] = f2bf(v);
                    if (accum) lsum += v * v;
                } else if (mode == 2) {
                    float v = rsrc[idx] + 0.1f * (c - bf2f(esub[idx]));
                    outf[idx] = v; outbf[idx] = f2bf(v);
                } else {
                    float v = 0.9f * rsrc[idx] + 0.1f * c;
                    outf[idx] = v; outbf[idx] = f2bf(v);
                    if (accum) lsum += v * v;
                }
            }
        }
    }

    if (accum) {
        lsum *= 0.5f;
#pragma unroll
        for (int o = 32; o > 0; o >>= 1) lsum += __shfl_down(lsum, o);
        if (lane == 0) red[wave] = lsum;
        __syncthreads();
        if (tid == 0) atomicAdd(errAcc, red[0] + red[1] + red[2] + red[3]);
    }
}

// ---------------- host ----------------

extern "C" void kernel_launch(void* const* d_in, const int* in_sizes, int n_in,
                              void* d_out, int out_size, void* d_ws, size_t ws_size,
                              hipStream_t stream) {
    const float* x  = (const float*)d_in[0];
    const float* W0 = (const float*)d_in[1];
    const float* b0 = (const float*)d_in[2];
    const float* W1 = (const float*)d_in[3];
    const float* b1 = (const float*)d_in[4];
    const float* W2 = (const float*)d_in[5];
    const float* b2 = (const float*)d_in[6];

    const int Bz = 4096;  // batch

    char* ws = (char*)d_ws;
    size_t off = 0;
    auto alloc = [&](size_t bytes) -> char* {
        char* p = ws + off;
        off += (bytes + 255) & ~(size_t)255;
        return p;
    };

    float* r1f = (float*)alloc((size_t)Bz * 2048 * 4);
    float* r2f = (float*)alloc((size_t)Bz * 2048 * 4);
    u16*   r1b = (u16*)  alloc((size_t)Bz * 2048 * 2);
    u16*   r2b = (u16*)  alloc((size_t)Bz * 2048 * 2);
    u16*   r3b = (u16*)  alloc((size_t)Bz * 512 * 2);
    u16*   e0b = (u16*)  alloc((size_t)Bz * 1024 * 2);
    u16*   e1b = (u16*)  alloc((size_t)Bz * 2048 * 2);
    u16*   e2b = (u16*)  alloc((size_t)Bz * 2048 * 2);
    u16*   xb  = (u16*)  alloc((size_t)Bz * 1024 * 2);
    u16*   W0b = (u16*)  alloc((size_t)2048 * 1024 * 2);
    u16*   W0t = (u16*)  alloc((size_t)1024 * 2048 * 2);
    u16*   W1b = (u16*)  alloc((size_t)2048 * 2048 * 2);
    u16*   W1t = (u16*)  alloc((size_t)2048 * 2048 * 2);
    u16*   W2b = (u16*)  alloc((size_t)512 * 2048 * 2);
    u16*   W2t = (u16*)  alloc((size_t)2048 * 512 * 2);

    float* r3f    = (float*)d_out;            // 4096 x 512
    float* errAcc = ((float*)d_out) + (size_t)Bz * 512;

    // conversions (cheap; recomputed every call so graph replay is identical)
    cvt_bf16<<<(Bz * 1024 / 4) / 256, 256, 0, stream>>>(x,  xb,  Bz * 1024 / 4);
    cvt_bf16<<<(2048 * 1024 / 4) / 256, 256, 0, stream>>>(W0, W0b, 2048 * 1024 / 4);
    cvt_bf16<<<(2048 * 2048 / 4) / 256, 256, 0, stream>>>(W1, W1b, 2048 * 2048 / 4);
    cvt_bf16<<<(512 * 2048 / 4) / 256, 256, 0, stream>>>(W2, W2b, 512 * 2048 / 4);
    transpose_cvt<<<dim3(1024 / 32, 2048 / 32), 256, 0, stream>>>(W0, W0t, 2048, 1024);
    transpose_cvt<<<dim3(2048 / 32, 2048 / 32), 256, 0, stream>>>(W1, W1t, 2048, 2048);
    transpose_cvt<<<dim3(2048 / 32, 512 / 32),  256, 0, stream>>>(W2, W2t, 512, 2048);

    hipMemsetAsync(errAcc, 0, 4, stream);

    auto gemm = [&](const u16* Ag, const u16* Bg, int K, int N,
                    const float* rsrc, const float* bias, const u16* esub,
                    float* outf, u16* outbf, int mode, int accum) {
        dim3 grid(N / 128, Bz / 128);
        pc_gemm_nt<<<grid, 256, 0, stream>>>(Ag, Bg, K, N, rsrc, bias, esub,
                                             outf, outbf, errAcc, mode, accum);
    };

    // forward init
    gemm(xb,  W0b, 1024, 2048, nullptr, b0, nullptr, r1f, r1b, 0, 0);
    gemm(r1b, W1b, 2048, 2048, nullptr, b1, nullptr, r2f, r2b, 0, 0);
    gemm(r2b, W2b, 2048, 512,  nullptr, b2, nullptr, r3f, r3b, 0, 0);

    // 20 relaxation steps
    for (int s = 0; s < 20; ++s) {
        int last = (s == 19) ? 1 : 0;
        // errors (old state)
        gemm(r3b, W2t, 512,  2048, r2f, nullptr, nullptr, nullptr, e2b, 1, 0);
        gemm(r2b, W1t, 2048, 2048, r1f, nullptr, nullptr, nullptr, e1b, 1, 0);
        gemm(r1b, W0t, 2048, 1024, x,   nullptr, nullptr, nullptr, e0b, 1, 0);
        // updates
        gemm(e0b, W0b, 1024, 2048, r1f, nullptr, e1b, r1f, r1b, 2, 0);
        gemm(e1b, W1b, 2048, 2048, r2f, nullptr, e2b, r2f, r2b, 2, 0);
        gemm(e2b, W2b, 2048, 512,  r3f, nullptr, nullptr, r3f, r3b, 3, last);
    }

    // final errors with 0.5*sum(e^2) accumulation (r3^2 added by last UPD3)
    gemm(r3b, W2t, 512,  2048, r2f, nullptr, nullptr, nullptr, e2b, 1, 1);
    gemm(r2b, W1t, 2048, 2048, r1f, nullptr, nullptr, nullptr, e1b, 1, 1);
    gemm(r1b, W0t, 2048, 1024, x,   nullptr, nullptr, nullptr, e0b, 1, 1);
}

// Round 2
// 7644.608 us; speedup vs baseline: 1.1861x; 1.1861x over previous
//
#include <hip/hip_runtime.h>

typedef unsigned short u16;
typedef __bf16 bf16_t;
typedef bf16_t bf16x8 __attribute__((ext_vector_type(8)));
typedef u16 u16x8 __attribute__((ext_vector_type(8)));
typedef float f32x4 __attribute__((ext_vector_type(4)));

__device__ __forceinline__ u16 f2bf(float f) {
    unsigned u = __builtin_bit_cast(unsigned, f);
    u += 0x7fffu + ((u >> 16) & 1u);   // RNE
    return (u16)(u >> 16);
}
__device__ __forceinline__ float bf2f(u16 h) {
    unsigned u = ((unsigned)h) << 16;
    return __builtin_bit_cast(float, u);
}
__device__ __forceinline__ float fast_tanh(float x) {
    x = fminf(fmaxf(x, -20.f), 20.f);
    float e = __expf(2.f * x);
    return (e - 1.f) * __builtin_amdgcn_rcpf(e + 1.f);
}

__device__ __forceinline__ void gload_lds16(const void* g, void* l) {
    __builtin_amdgcn_global_load_lds((__attribute__((address_space(1))) void*)(g),
                                     (__attribute__((address_space(3))) void*)(l),
                                     16, 0, 0);
}

// ---------------- conversion kernels ----------------

__global__ void cvt_bf16(const float* __restrict__ src, u16* __restrict__ dst, int n4) {
    int i = blockIdx.x * blockDim.x + threadIdx.x;
    if (i < n4) {
        float4 v = ((const float4*)src)[i];
        ushort4 o;
        o.x = f2bf(v.x); o.y = f2bf(v.y); o.z = f2bf(v.z); o.w = f2bf(v.w);
        ((ushort4*)dst)[i] = o;
    }
}

// W: R x C fp32  ->  WT: C x R bf16
__global__ void transpose_cvt(const float* __restrict__ W, u16* __restrict__ WT, int R, int C) {
    __shared__ float tile[32][33];
    int c0 = blockIdx.x * 32, r0 = blockIdx.y * 32;
    int tx = threadIdx.x & 31, ty = threadIdx.x >> 5;  // 32x8
#pragma unroll
    for (int i = 0; i < 32; i += 8)
        tile[ty + i][tx] = W[(size_t)(r0 + ty + i) * C + (c0 + tx)];
    __syncthreads();
#pragma unroll
    for (int i = 0; i < 32; i += 8)
        WT[(size_t)(c0 + ty + i) * R + (r0 + tx)] = f2bf(tile[tx][ty + i]);
}

// ---------------- segmented fused NT GEMM phase ----------------
// Each segment: C[m,n] = sum_k A[m,k]*B[n,k]; A: 4096 x K (lda=K), B: N x K (ldb=K)
// mode 0 (FWD):  v = tanh(C + bias[n]);               write outf, outbf
// mode 1 (ERR):  v = rsrc - tanh(C);                  write outbf        (+ 0.5 v^2 if accum)
// mode 2 (UPD):  v = rsrc + 0.1*(C - bf2f(esub));     write outf, outbf
// mode 3 (UPD3): v = 0.9*rsrc + 0.1*C;                write outf, outbf  (+ 0.5 v^2 if accum)

struct Seg {
    const u16* A; const u16* B;
    const float* rsrc; const float* bias;
    const u16* esub;
    float* outf; u16* outbf;
    int K, N, nCols, blkStart, mode, accum;
};
struct Phase {
    Seg seg[3];
    int bEnd0, bEnd1;   // segment boundaries in linear block space
};

__global__ __launch_bounds__(256) void pc_phase(Phase ph, float* __restrict__ errAcc) {
    __shared__ u16 As[4096];   // [kb 0..3][row 0..127][8]
    __shared__ u16 Bs[4096];
    __shared__ float red[4];

    const int bid = blockIdx.x;
    Seg sg;
    if (bid < ph.bEnd0) sg = ph.seg[0];
    else if (bid < ph.bEnd1) sg = ph.seg[1];
    else sg = ph.seg[2];

    const int local = bid - sg.blkStart;
    const int bx = local % sg.nCols;
    const int by = local / sg.nCols;
    const int K = sg.K, N = sg.N;

    const int tid  = threadIdx.x;
    const int wave = tid >> 6, lane = tid & 63;
    const int q    = lane >> 4, ln = lane & 15;
    const int wrow = (wave >> 1) * 64, wcol = (wave & 1) * 64;

    const int rowA0 = by * 128;
    const int rowB0 = bx * 128;

    const u16* gA0 = sg.A + (size_t)(rowA0 + lane) * K + wave * 8;
    const u16* gA1 = sg.A + (size_t)(rowA0 + 64 + lane) * K + wave * 8;
    const u16* gB0 = sg.B + (size_t)(rowB0 + lane) * K + wave * 8;
    const u16* gB1 = sg.B + (size_t)(rowB0 + 64 + lane) * K + wave * 8;
    u16* lA0 = &As[wave * 1024];
    u16* lA1 = &As[wave * 1024 + 512];
    u16* lB0 = &Bs[wave * 1024];
    u16* lB1 = &Bs[wave * 1024 + 512];

    f32x4 acc[4][4];
#pragma unroll
    for (int i = 0; i < 4; ++i)
#pragma unroll
        for (int j = 0; j < 4; ++j)
            acc[i][j] = (f32x4){0.f, 0.f, 0.f, 0.f};

    for (int k0 = 0; k0 < K; k0 += 32) {
        gload_lds16(gA0 + k0, lA0);
        gload_lds16(gA1 + k0, lA1);
        gload_lds16(gB0 + k0, lB0);
        gload_lds16(gB1 + k0, lB1);
        __syncthreads();

        bf16x8 a[4], b[4];
#pragma unroll
        for (int mt = 0; mt < 4; ++mt)
            a[mt] = __builtin_bit_cast(bf16x8,
                *(const u16x8*)&As[q * 1024 + (wrow + mt * 16 + ln) * 8]);
#pragma unroll
        for (int nt = 0; nt < 4; ++nt)
            b[nt] = __builtin_bit_cast(bf16x8,
                *(const u16x8*)&Bs[q * 1024 + (wcol + nt * 16 + ln) * 8]);
#pragma unroll
        for (int mt = 0; mt < 4; ++mt)
#pragma unroll
            for (int nt = 0; nt < 4; ++nt)
                acc[mt][nt] = __builtin_amdgcn_mfma_f32_16x16x32_bf16(
                    a[mt], b[nt], acc[mt][nt], 0, 0, 0);
        __syncthreads();
    }

    // epilogue: C/D layout col = lane&15 (n), row = q*4 + reg (m)
    float lsum = 0.f;
    const int mode = sg.mode;
    const int ncol0 = rowB0 + wcol + ln;
#pragma unroll
    for (int mt = 0; mt < 4; ++mt) {
#pragma unroll
        for (int r = 0; r < 4; ++r) {
            int m = rowA0 + wrow + mt * 16 + q * 4 + r;
            size_t offm = (size_t)m * N;
#pragma unroll
            for (int nt = 0; nt < 4; ++nt) {
                int n = ncol0 + nt * 16;
                size_t idx = offm + n;
                float c = acc[mt][nt][r];
                if (mode == 0) {
                    float v = fast_tanh(c + sg.bias[n]);
                    sg.outf[idx] = v; sg.outbf[idx] = f2bf(v);
                } else if (mode == 1) {
                    float v = sg.rsrc[idx] - fast_tanh(c);
                    sg.outbf[idx] = f2bf(v);
                    if (sg.accum) lsum += v * v;
                } else if (mode == 2) {
                    float v = sg.rsrc[idx] + 0.1f * (c - bf2f(sg.esub[idx]));
                    sg.outf[idx] = v; sg.outbf[idx] = f2bf(v);
                } else {
                    float v = 0.9f * sg.rsrc[idx] + 0.1f * c;
                    sg.outf[idx] = v; sg.outbf[idx] = f2bf(v);
                    if (sg.accum) lsum += v * v;
                }
            }
        }
    }

    if (sg.accum) {
        lsum *= 0.5f;
#pragma unroll
        for (int o = 32; o > 0; o >>= 1) lsum += __shfl_down(lsum, o);
        if (lane == 0) red[wave] = lsum;
        __syncthreads();
        if (tid == 0) atomicAdd(errAcc, red[0] + red[1] + red[2] + red[3]);
    }
}

// ---------------- host ----------------

extern "C" void kernel_launch(void* const* d_in, const int* in_sizes, int n_in,
                              void* d_out, int out_size, void* d_ws, size_t ws_size,
                              hipStream_t stream) {
    const float* x  = (const float*)d_in[0];
    const float* W0 = (const float*)d_in[1];
    const float* b0 = (const float*)d_in[2];
    const float* W1 = (const float*)d_in[3];
    const float* b1 = (const float*)d_in[4];
    const float* W2 = (const float*)d_in[5];
    const float* b2 = (const float*)d_in[6];

    const int Bz = 4096;  // batch

    char* ws = (char*)d_ws;
    size_t off = 0;
    auto alloc = [&](size_t bytes) -> char* {
        char* p = ws + off;
        off += (bytes + 255) & ~(size_t)255;
        return p;
    };

    float* r1f = (float*)alloc((size_t)Bz * 2048 * 4);
    float* r2f = (float*)alloc((size_t)Bz * 2048 * 4);
    u16*   r1b = (u16*)  alloc((size_t)Bz * 2048 * 2);
    u16*   r2b = (u16*)  alloc((size_t)Bz * 2048 * 2);
    u16*   r3b = (u16*)  alloc((size_t)Bz * 512 * 2);
    u16*   e0b = (u16*)  alloc((size_t)Bz * 1024 * 2);
    u16*   e1b = (u16*)  alloc((size_t)Bz * 2048 * 2);
    u16*   e2b = (u16*)  alloc((size_t)Bz * 2048 * 2);
    u16*   xb  = (u16*)  alloc((size_t)Bz * 1024 * 2);
    u16*   W0b = (u16*)  alloc((size_t)2048 * 1024 * 2);
    u16*   W0t = (u16*)  alloc((size_t)1024 * 2048 * 2);
    u16*   W1b = (u16*)  alloc((size_t)2048 * 2048 * 2);
    u16*   W1t = (u16*)  alloc((size_t)2048 * 2048 * 2);
    u16*   W2b = (u16*)  alloc((size_t)512 * 2048 * 2);
    u16*   W2t = (u16*)  alloc((size_t)2048 * 512 * 2);

    float* r3f    = (float*)d_out;            // 4096 x 512
    float* errAcc = ((float*)d_out) + (size_t)Bz * 512;

    cvt_bf16<<<(Bz * 1024 / 4) / 256, 256, 0, stream>>>(x,  xb,  Bz * 1024 / 4);
    cvt_bf16<<<(2048 * 1024 / 4) / 256, 256, 0, stream>>>(W0, W0b, 2048 * 1024 / 4);
    cvt_bf16<<<(2048 * 2048 / 4) / 256, 256, 0, stream>>>(W1, W1b, 2048 * 2048 / 4);
    cvt_bf16<<<(512 * 2048 / 4) / 256, 256, 0, stream>>>(W2, W2b, 512 * 2048 / 4);
    transpose_cvt<<<dim3(1024 / 32, 2048 / 32), 256, 0, stream>>>(W0, W0t, 2048, 1024);
    transpose_cvt<<<dim3(2048 / 32, 2048 / 32), 256, 0, stream>>>(W1, W1t, 2048, 2048);
    transpose_cvt<<<dim3(2048 / 32, 512 / 32),  256, 0, stream>>>(W2, W2t, 512, 2048);

    hipMemsetAsync(errAcc, 0, 4, stream);

    auto mkseg = [&](const u16* A, const u16* B, int K, int N,
                     const float* rsrc, const float* bias, const u16* esub,
                     float* outf, u16* outbf, int mode, int accum, int blkStart) {
        Seg s;
        s.A = A; s.B = B; s.rsrc = rsrc; s.bias = bias; s.esub = esub;
        s.outf = outf; s.outbf = outbf;
        s.K = K; s.N = N; s.nCols = N / 128; s.blkStart = blkStart;
        s.mode = mode; s.accum = accum;
        return s;
    };
    auto nblk = [&](int N) { return (N / 128) * (Bz / 128); };

    auto launch1 = [&](Seg s0) {
        Phase ph;
        int b0 = nblk(s0.N);
        ph.seg[0] = s0; ph.seg[1] = s0; ph.seg[2] = s0;
        ph.bEnd0 = b0; ph.bEnd1 = b0;
        pc_phase<<<b0, 256, 0, stream>>>(ph, errAcc);
    };
    auto launch3 = [&](Seg s0, Seg s1, Seg s2) {
        Phase ph;
        int b0 = nblk(s0.N), b1 = nblk(s1.N), b2 = nblk(s2.N);
        s1.blkStart = b0; s2.blkStart = b0 + b1;
        ph.seg[0] = s0; ph.seg[1] = s1; ph.seg[2] = s2;
        ph.bEnd0 = b0; ph.bEnd1 = b0 + b1;
        pc_phase<<<b0 + b1 + b2, 256, 0, stream>>>(ph, errAcc);
    };

    // forward init (sequential dependency)
    launch1(mkseg(xb,  W0b, 1024, 2048, nullptr, b0, nullptr, r1f, r1b, 0, 0, 0));
    launch1(mkseg(r1b, W1b, 2048, 2048, nullptr, b1, nullptr, r2f, r2b, 0, 0, 0));
    launch1(mkseg(r2b, W2b, 2048, 512,  nullptr, b2, nullptr, r3f, r3b, 0, 0, 0));

    // 20 relaxation steps: fused error phase, fused update phase
    for (int s = 0; s < 20; ++s) {
        int last = (s == 19) ? 1 : 0;
        // errors (independent; descending K for schedule balance)
        launch3(mkseg(r2b, W1t, 2048, 2048, r1f, nullptr, nullptr, nullptr, e1b, 1, 0, 0),
                mkseg(r1b, W0t, 2048, 1024, x,   nullptr, nullptr, nullptr, e0b, 1, 0, 0),
                mkseg(r3b, W2t, 512,  2048, r2f, nullptr, nullptr, nullptr, e2b, 1, 0, 0));
        // updates (independent; descending K)
        launch3(mkseg(e1b, W1b, 2048, 2048, r2f, nullptr, e2b, r2f, r2b, 2, 0, 0),
                mkseg(e2b, W2b, 2048, 512,  r3f, nullptr, nullptr, r3f, r3b, 3, last, 0),
                mkseg(e0b, W0b, 1024, 2048, r1f, nullptr, e1b, r1f, r1b, 2, 0, 0));
    }

    // final errors with 0.5*sum(e^2) accumulation (r3^2 added by last UPD3)
    launch3(mkseg(r2b, W1t, 2048, 2048, r1f, nullptr, nullptr, nullptr, e1b, 1, 1, 0),
            mkseg(r1b, W0t, 2048, 1024, x,   nullptr, nullptr, nullptr, e0b, 1, 1, 0),
            mkseg(r3b, W2t, 512,  2048, r2f, nullptr, nullptr, nullptr, e2b, 1, 1, 0));
}

// Round 3
// 7359.093 us; speedup vs baseline: 1.2321x; 1.0388x over previous
//
#include <hip/hip_runtime.h>

typedef unsigned short u16;
typedef __bf16 bf16_t;
typedef bf16_t bf16x8 __attribute__((ext_vector_type(8)));
typedef u16 u16x8 __attribute__((ext_vector_type(8)));
typedef float f32x4 __attribute__((ext_vector_type(4)));

__device__ __forceinline__ u16 f2bf(float f) {
    unsigned u = __builtin_bit_cast(unsigned, f);
    u += 0x7fffu + ((u >> 16) & 1u);   // RNE
    return (u16)(u >> 16);
}
__device__ __forceinline__ float bf2f(u16 h) {
    unsigned u = ((unsigned)h) << 16;
    return __builtin_bit_cast(float, u);
}
__device__ __forceinline__ float fast_tanh(float x) {
    x = fminf(fmaxf(x, -20.f), 20.f);
    float e = __expf(2.f * x);
    return (e - 1.f) * __builtin_amdgcn_rcpf(e + 1.f);
}

__device__ __forceinline__ void gload_lds16(const void* g, void* l) {
    __builtin_amdgcn_global_load_lds((__attribute__((address_space(1))) void*)(g),
                                     (__attribute__((address_space(3))) void*)(l),
                                     16, 0, 0);
}

// ---------------- conversion kernels ----------------

__global__ void cvt_bf16(const float* __restrict__ src, u16* __restrict__ dst, int n4) {
    int i = blockIdx.x * blockDim.x + threadIdx.x;
    if (i < n4) {
        float4 v = ((const float4*)src)[i];
        ushort4 o;
        o.x = f2bf(v.x); o.y = f2bf(v.y); o.z = f2bf(v.z); o.w = f2bf(v.w);
        ((ushort4*)dst)[i] = o;
    }
}

// W: R x C fp32  ->  WT: C x R bf16
__global__ void transpose_cvt(const float* __restrict__ W, u16* __restrict__ WT, int R, int C) {
    __shared__ float tile[32][33];
    int c0 = blockIdx.x * 32, r0 = blockIdx.y * 32;
    int tx = threadIdx.x & 31, ty = threadIdx.x >> 5;  // 32x8
#pragma unroll
    for (int i = 0; i < 32; i += 8)
        tile[ty + i][tx] = W[(size_t)(r0 + ty + i) * C + (c0 + tx)];
    __syncthreads();
#pragma unroll
    for (int i = 0; i < 32; i += 8)
        WT[(size_t)(c0 + ty + i) * R + (r0 + tx)] = f2bf(tile[tx][ty + i]);
}

// ---------------- segmented fused NT GEMM phase (double-buffered) ----------------
// Each segment: C[m,n] = sum_k A[m,k]*B[n,k]; A: 4096 x K (lda=K), B: N x K (ldb=K)
// mode 0 (FWD):  v = tanh(C + bias[n]);               write outf, outbf
// mode 1 (ERR):  v = rsrc - tanh(C);                  write outbf        (+ 0.5 v^2 if accum)
// mode 2 (UPD):  v = rsrc + 0.1*(C - bf2f(esub));     write outf, outbf
// mode 3 (UPD3): v = 0.9*rsrc + 0.1*C;                write outf, outbf  (+ 0.5 v^2 if accum)

struct Seg {
    const u16* A; const u16* B;
    const float* rsrc; const float* bias;
    const u16* esub;
    float* outf; u16* outbf;
    int K, N, blkStart, mode, accum;
};
struct Phase {
    Seg seg[3];
    int bEnd0, bEnd1;   // segment boundaries in linear block space
};

__global__ __launch_bounds__(256) void pc_phase(Phase ph, float* __restrict__ errAcc) {
    // double-buffered: [buf][kb 0..3][row 0..127][8]
    __shared__ u16 As[2][4096];
    __shared__ u16 Bs[2][4096];
    __shared__ float red[4];

    const int bid = blockIdx.x;
    Seg sg;
    if (bid < ph.bEnd0) sg = ph.seg[0];
    else if (bid < ph.bEnd1) sg = ph.seg[1];
    else sg = ph.seg[2];

    const int local = bid - sg.blkStart;
    // weight-tile-major ordering: 32 consecutive blocks share one B (weight) tile
    const int bx = local >> 5;        // N-tile (weight rows 128*bx ..)
    const int by = local & 31;        // M-tile (batch rows)
    const int K = sg.K, N = sg.N;

    const int tid  = threadIdx.x;
    const int wave = tid >> 6, lane = tid & 63;
    const int q    = lane >> 4, ln = lane & 15;
    const int wrow = (wave >> 1) * 64, wcol = (wave & 1) * 64;

    const int rowA0 = by * 128;
    const int rowB0 = bx * 128;

    const u16* gA0 = sg.A + (size_t)(rowA0 + lane) * K + wave * 8;
    const u16* gA1 = sg.A + (size_t)(rowA0 + 64 + lane) * K + wave * 8;
    const u16* gB0 = sg.B + (size_t)(rowB0 + lane) * K + wave * 8;
    const u16* gB1 = sg.B + (size_t)(rowB0 + 64 + lane) * K + wave * 8;
    const int lofs = wave * 1024;

    f32x4 acc[4][4];
#pragma unroll
    for (int i = 0; i < 4; ++i)
#pragma unroll
        for (int j = 0; j < 4; ++j)
            acc[i][j] = (f32x4){0.f, 0.f, 0.f, 0.f};

    const int niter = K >> 5;

    // prologue: stage tile 0 into buffer 0
    gload_lds16(gA0, &As[0][lofs]);
    gload_lds16(gA1, &As[0][lofs + 512]);
    gload_lds16(gB0, &Bs[0][lofs]);
    gload_lds16(gB1, &Bs[0][lofs + 512]);
    __syncthreads();

    for (int k = 0; k < niter; ++k) {
        // prefetch tile k+1 into the other buffer BEFORE computing on tile k;
        // the end-of-iter barrier's vmcnt drain then overlaps with the MFMAs below
        if (k + 1 < niter) {
            const int off2 = (k + 1) << 5;
            const int b2 = (k + 1) & 1;
            gload_lds16(gA0 + off2, &As[b2][lofs]);
            gload_lds16(gA1 + off2, &As[b2][lofs + 512]);
            gload_lds16(gB0 + off2, &Bs[b2][lofs]);
            gload_lds16(gB1 + off2, &Bs[b2][lofs + 512]);
        }
        const u16* as = As[k & 1];
        const u16* bs = Bs[k & 1];

        bf16x8 a[4], b[4];
#pragma unroll
        for (int mt = 0; mt < 4; ++mt)
            a[mt] = __builtin_bit_cast(bf16x8,
                *(const u16x8*)&as[q * 1024 + (wrow + mt * 16 + ln) * 8]);
#pragma unroll
        for (int nt = 0; nt < 4; ++nt)
            b[nt] = __builtin_bit_cast(bf16x8,
                *(const u16x8*)&bs[q * 1024 + (wcol + nt * 16 + ln) * 8]);
#pragma unroll
        for (int mt = 0; mt < 4; ++mt)
#pragma unroll
            for (int nt = 0; nt < 4; ++nt)
                acc[mt][nt] = __builtin_amdgcn_mfma_f32_16x16x32_bf16(
                    a[mt], b[nt], acc[mt][nt], 0, 0, 0);
        __syncthreads();   // (a) all reads of buf[k&1] done; (b) buf[(k+1)&1] staged
    }

    // epilogue: C/D layout col = lane&15 (n), row = q*4 + reg (m)
    float lsum = 0.f;
    const int mode = sg.mode;
    const int ncol0 = rowB0 + wcol + ln;
#pragma unroll
    for (int mt = 0; mt < 4; ++mt) {
#pragma unroll
        for (int r = 0; r < 4; ++r) {
            int m = rowA0 + wrow + mt * 16 + q * 4 + r;
            size_t offm = (size_t)m * N;
#pragma unroll
            for (int nt = 0; nt < 4; ++nt) {
                int n = ncol0 + nt * 16;
                size_t idx = offm + n;
                float c = acc[mt][nt][r];
                if (mode == 0) {
                    float v = fast_tanh(c + sg.bias[n]);
                    sg.outf[idx] = v; sg.outbf[idx] = f2bf(v);
                } else if (mode == 1) {
                    float v = sg.rsrc[idx] - fast_tanh(c);
                    sg.outbf[idx] = f2bf(v);
                    if (sg.accum) lsum += v * v;
                } else if (mode == 2) {
                    float v = sg.rsrc[idx] + 0.1f * (c - bf2f(sg.esub[idx]));
                    sg.outf[idx] = v; sg.outbf[idx] = f2bf(v);
                } else {
                    float v = 0.9f * sg.rsrc[idx] + 0.1f * c;
                    sg.outf[idx] = v; sg.outbf[idx] = f2bf(v);
                    if (sg.accum) lsum += v * v;
                }
            }
        }
    }

    if (sg.accum) {
        lsum *= 0.5f;
#pragma unroll
        for (int o = 32; o > 0; o >>= 1) lsum += __shfl_down(lsum, o);
        if (lane == 0) red[wave] = lsum;
        __syncthreads();
        if (tid == 0) atomicAdd(errAcc, red[0] + red[1] + red[2] + red[3]);
    }
}

// ---------------- host ----------------

extern "C" void kernel_launch(void* const* d_in, const int* in_sizes, int n_in,
                              void* d_out, int out_size, void* d_ws, size_t ws_size,
                              hipStream_t stream) {
    const float* x  = (const float*)d_in[0];
    const float* W0 = (const float*)d_in[1];
    const float* b0 = (const float*)d_in[2];
    const float* W1 = (const float*)d_in[3];
    const float* b1 = (const float*)d_in[4];
    const float* W2 = (const float*)d_in[5];
    const float* b2 = (const float*)d_in[6];

    const int Bz = 4096;  // batch

    char* ws = (char*)d_ws;
    size_t off = 0;
    auto alloc = [&](size_t bytes) -> char* {
        char* p = ws + off;
        off += (bytes + 255) & ~(size_t)255;
        return p;
    };

    float* r1f = (float*)alloc((size_t)Bz * 2048 * 4);
    float* r2f = (float*)alloc((size_t)Bz * 2048 * 4);
    u16*   r1b = (u16*)  alloc((size_t)Bz * 2048 * 2);
    u16*   r2b = (u16*)  alloc((size_t)Bz * 2048 * 2);
    u16*   r3b = (u16*)  alloc((size_t)Bz * 512 * 2);
    u16*   e0b = (u16*)  alloc((size_t)Bz * 1024 * 2);
    u16*   e1b = (u16*)  alloc((size_t)Bz * 2048 * 2);
    u16*   e2b = (u16*)  alloc((size_t)Bz * 2048 * 2);
    u16*   xb  = (u16*)  alloc((size_t)Bz * 1024 * 2);
    u16*   W0b = (u16*)  alloc((size_t)2048 * 1024 * 2);
    u16*   W0t = (u16*)  alloc((size_t)1024 * 2048 * 2);
    u16*   W1b = (u16*)  alloc((size_t)2048 * 2048 * 2);
    u16*   W1t = (u16*)  alloc((size_t)2048 * 2048 * 2);
    u16*   W2b = (u16*)  alloc((size_t)512 * 2048 * 2);
    u16*   W2t = (u16*)  alloc((size_t)2048 * 512 * 2);

    float* r3f    = (float*)d_out;            // 4096 x 512
    float* errAcc = ((float*)d_out) + (size_t)Bz * 512;

    cvt_bf16<<<(Bz * 1024 / 4) / 256, 256, 0, stream>>>(x,  xb,  Bz * 1024 / 4);
    cvt_bf16<<<(2048 * 1024 / 4) / 256, 256, 0, stream>>>(W0, W0b, 2048 * 1024 / 4);
    cvt_bf16<<<(2048 * 2048 / 4) / 256, 256, 0, stream>>>(W1, W1b, 2048 * 2048 / 4);
    cvt_bf16<<<(512 * 2048 / 4) / 256, 256, 0, stream>>>(W2, W2b, 512 * 2048 / 4);
    transpose_cvt<<<dim3(1024 / 32, 2048 / 32), 256, 0, stream>>>(W0, W0t, 2048, 1024);
    transpose_cvt<<<dim3(2048 / 32, 2048 / 32), 256, 0, stream>>>(W1, W1t, 2048, 2048);
    transpose_cvt<<<dim3(2048 / 32, 512 / 32),  256, 0, stream>>>(W2, W2t, 512, 2048);

    hipMemsetAsync(errAcc, 0, 4, stream);

    auto mkseg = [&](const u16* A, const u16* B, int K, int N,
                     const float* rsrc, const float* bias, const u16* esub,
                     float* outf, u16* outbf, int mode, int accum, int blkStart) {
        Seg s;
        s.A = A; s.B = B; s.rsrc = rsrc; s.bias = bias; s.esub = esub;
        s.outf = outf; s.outbf = outbf;
        s.K = K; s.N = N; s.blkStart = blkStart;
        s.mode = mode; s.accum = accum;
        return s;
    };
    auto nblk = [&](int N) { return (N / 128) * (Bz / 128); };

    auto launch1 = [&](Seg s0) {
        Phase ph;
        int b0 = nblk(s0.N);
        ph.seg[0] = s0; ph.seg[1] = s0; ph.seg[2] = s0;
        ph.bEnd0 = b0; ph.bEnd1 = b0;
        pc_phase<<<b0, 256, 0, stream>>>(ph, errAcc);
    };
    auto launch3 = [&](Seg s0, Seg s1, Seg s2) {
        Phase ph;
        int b0 = nblk(s0.N), b1 = nblk(s1.N), b2 = nblk(s2.N);
        s1.blkStart = b0; s2.blkStart = b0 + b1;
        ph.seg[0] = s0; ph.seg[1] = s1; ph.seg[2] = s2;
        ph.bEnd0 = b0; ph.bEnd1 = b0 + b1;
        pc_phase<<<b0 + b1 + b2, 256, 0, stream>>>(ph, errAcc);
    };

    // forward init (sequential dependency)
    launch1(mkseg(xb,  W0b, 1024, 2048, nullptr, b0, nullptr, r1f, r1b, 0, 0, 0));
    launch1(mkseg(r1b, W1b, 2048, 2048, nullptr, b1, nullptr, r2f, r2b, 0, 0, 0));
    launch1(mkseg(r2b, W2b, 2048, 512,  nullptr, b2, nullptr, r3f, r3b, 0, 0, 0));

    // 20 relaxation steps: fused error phase, fused update phase
    for (int s = 0; s < 20; ++s) {
        int last = (s == 19) ? 1 : 0;
        // errors (independent; descending K for schedule balance)
        launch3(mkseg(r2b, W1t, 2048, 2048, r1f, nullptr, nullptr, nullptr, e1b, 1, 0, 0),
                mkseg(r1b, W0t, 2048, 1024, x,   nullptr, nullptr, nullptr, e0b, 1, 0, 0),
                mkseg(r3b, W2t, 512,  2048, r2f, nullptr, nullptr, nullptr, e2b, 1, 0, 0));
        // updates (independent; descending K)
        launch3(mkseg(e1b, W1b, 2048, 2048, r2f, nullptr, e2b, r2f, r2b, 2, 0, 0),
                mkseg(e2b, W2b, 2048, 512,  r3f, nullptr, nullptr, r3f, r3b, 3, last, 0),
                mkseg(e0b, W0b, 1024, 2048, r1f, nullptr, e1b, r1f, r1b, 2, 0, 0));
    }

    // final errors with 0.5*sum(e^2) accumulation (r3^2 added by last UPD3)
    launch3(mkseg(r2b, W1t, 2048, 2048, r1f, nullptr, nullptr, nullptr, e1b, 1, 1, 0),
            mkseg(r1b, W0t, 2048, 1024, x,   nullptr, nullptr, nullptr, e0b, 1, 1, 0),
            mkseg(r3b, W2t, 512,  2048, r2f, nullptr, nullptr, nullptr, e2b, 1, 1, 0));
}

// Round 4
// 7328.132 us; speedup vs baseline: 1.2373x; 1.0042x over previous
//
#include <hip/hip_runtime.h>

typedef unsigned short u16;
typedef __bf16 bf16_t;
typedef bf16_t bf16x8 __attribute__((ext_vector_type(8)));
typedef u16 u16x8 __attribute__((ext_vector_type(8)));
typedef float f32x4 __attribute__((ext_vector_type(4)));

__device__ __forceinline__ u16 f2bf(float f) {
    unsigned u = __builtin_bit_cast(unsigned, f);
    u += 0x7fffu + ((u >> 16) & 1u);   // RNE
    return (u16)(u >> 16);
}
__device__ __forceinline__ float bf2f(u16 h) {
    unsigned u = ((unsigned)h) << 16;
    return __builtin_bit_cast(float, u);
}
__device__ __forceinline__ float fast_tanh(float x) {
    x = fminf(fmaxf(x, -20.f), 20.f);
    float e = __expf(2.f * x);
    return (e - 1.f) * __builtin_amdgcn_rcpf(e + 1.f);
}

__device__ __forceinline__ void gload_lds16(const void* g, void* l) {
    __builtin_amdgcn_global_load_lds((__attribute__((address_space(1))) void*)(g),
                                     (__attribute__((address_space(3))) void*)(l),
                                     16, 0, 0);
}

// ---------------- conversion kernels ----------------

__global__ void cvt_bf16(const float* __restrict__ src, u16* __restrict__ dst, int n4) {
    int i = blockIdx.x * blockDim.x + threadIdx.x;
    if (i < n4) {
        float4 v = ((const float4*)src)[i];
        ushort4 o;
        o.x = f2bf(v.x); o.y = f2bf(v.y); o.z = f2bf(v.z); o.w = f2bf(v.w);
        ((ushort4*)dst)[i] = o;
    }
}

// W: R x C fp32  ->  WT: C x R bf16
__global__ void transpose_cvt(const float* __restrict__ W, u16* __restrict__ WT, int R, int C) {
    __shared__ float tile[32][33];
    int c0 = blockIdx.x * 32, r0 = blockIdx.y * 32;
    int tx = threadIdx.x & 31, ty = threadIdx.x >> 5;  // 32x8
#pragma unroll
    for (int i = 0; i < 32; i += 8)
        tile[ty + i][tx] = W[(size_t)(r0 + ty + i) * C + (c0 + tx)];
    __syncthreads();
#pragma unroll
    for (int i = 0; i < 32; i += 8)
        WT[(size_t)(c0 + ty + i) * R + (r0 + tx)] = f2bf(tile[tx][ty + i]);
}

// ---------------- segmented fused NT GEMM phase (BK=64, single buffer) ----------------
// Each segment: C[m,n] = sum_k A[m,k]*B[n,k]; A: 4096 x K (lda=K), B: N x K (ldb=K)
// mode 0 (FWD):  v = tanh(C + bias[n]);               write outf, outbf
// mode 1 (ERR):  v = rsrc - tanh(C);                  write outbf        (+ 0.5 v^2 if accum)
// mode 2 (UPD):  v = rsrc + 0.1*(C - bf2f(esub));     write outf, outbf
// mode 3 (UPD3): v = 0.9*rsrc + 0.1*C;                write outf, outbf  (+ 0.5 v^2 if accum)

struct Seg {
    const u16* A; const u16* B;
    const float* rsrc; const float* bias;
    const u16* esub;
    float* outf; u16* outbf;
    int K, N, blkStart, mode, accum;
};
struct Phase {
    Seg seg[3];
    int bEnd0, bEnd1;   // segment boundaries in linear block space
};

__global__ __launch_bounds__(256) void pc_phase(Phase ph, float* __restrict__ errAcc) {
    // [kb 0..7][row 0..127][8]  — BK=64, 16 KB each
    __shared__ u16 As[8192];
    __shared__ u16 Bs[8192];
    __shared__ float red[4];

    const int bid = blockIdx.x;
    Seg sg;
    if (bid < ph.bEnd0) sg = ph.seg[0];
    else if (bid < ph.bEnd1) sg = ph.seg[1];
    else sg = ph.seg[2];

    const int local = bid - sg.blkStart;
    // weight-tile-major ordering: 32 consecutive blocks share one B (weight) tile
    const int bx = local >> 5;        // N-tile (weight rows 128*bx ..)
    const int by = local & 31;        // M-tile (batch rows)
    const int K = sg.K, N = sg.N;

    const int tid  = threadIdx.x;
    const int wave = tid >> 6, lane = tid & 63;
    const int q    = lane >> 4, ln = lane & 15;
    const int wrow = (wave >> 1) * 64, wcol = (wave & 1) * 64;

    const int rowA0 = by * 128;
    const int rowB0 = bx * 128;

    // staging: wave w handles kblocks w and w+4 (k-offsets w*8 and 32+w*8),
    // rows [0,64) and [64,128), for both A and B. 8 loads x 1 KB per wave.
    const u16* gA0 = sg.A + (size_t)(rowA0 + lane) * K + wave * 8;
    const u16* gA1 = sg.A + (size_t)(rowA0 + 64 + lane) * K + wave * 8;
    const u16* gB0 = sg.B + (size_t)(rowB0 + lane) * K + wave * 8;
    const u16* gB1 = sg.B + (size_t)(rowB0 + 64 + lane) * K + wave * 8;
    u16* lA0 = &As[wave * 1024];          // kb=wave, rows 0-63
    u16* lA1 = &As[wave * 1024 + 512];    // kb=wave, rows 64-127
    u16* lA2 = &As[(wave + 4) * 1024];        // kb=wave+4
    u16* lA3 = &As[(wave + 4) * 1024 + 512];
    u16* lB0 = &Bs[wave * 1024];
    u16* lB1 = &Bs[wave * 1024 + 512];
    u16* lB2 = &Bs[(wave + 4) * 1024];
    u16* lB3 = &Bs[(wave + 4) * 1024 + 512];

    f32x4 acc[4][4];
#pragma unroll
    for (int i = 0; i < 4; ++i)
#pragma unroll
        for (int j = 0; j < 4; ++j)
            acc[i][j] = (f32x4){0.f, 0.f, 0.f, 0.f};

    for (int k0 = 0; k0 < K; k0 += 64) {
        gload_lds16(gA0 + k0, lA0);
        gload_lds16(gA1 + k0, lA1);
        gload_lds16(gA0 + k0 + 32, lA2);
        gload_lds16(gA1 + k0 + 32, lA3);
        gload_lds16(gB0 + k0, lB0);
        gload_lds16(gB1 + k0, lB1);
        gload_lds16(gB0 + k0 + 32, lB2);
        gload_lds16(gB1 + k0 + 32, lB3);
        __syncthreads();

#pragma unroll
        for (int s = 0; s < 2; ++s) {
            const u16* as = &As[(s * 4 + q) * 1024];
            const u16* bs = &Bs[(s * 4 + q) * 1024];
            bf16x8 a[4], b[4];
#pragma unroll
            for (int mt = 0; mt < 4; ++mt)
                a[mt] = __builtin_bit_cast(bf16x8,
                    *(const u16x8*)&as[(wrow + mt * 16 + ln) * 8]);
#pragma unroll
            for (int nt = 0; nt < 4; ++nt)
                b[nt] = __builtin_bit_cast(bf16x8,
                    *(const u16x8*)&bs[(wcol + nt * 16 + ln) * 8]);
#pragma unroll
            for (int mt = 0; mt < 4; ++mt)
#pragma unroll
                for (int nt = 0; nt < 4; ++nt)
                    acc[mt][nt] = __builtin_amdgcn_mfma_f32_16x16x32_bf16(
                        a[mt], b[nt], acc[mt][nt], 0, 0, 0);
        }
        __syncthreads();
    }

    // epilogue: C/D layout col = lane&15 (n), row = q*4 + reg (m)
    float lsum = 0.f;
    const int mode = sg.mode;
    const int ncol0 = rowB0 + wcol + ln;
#pragma unroll
    for (int mt = 0; mt < 4; ++mt) {
#pragma unroll
        for (int r = 0; r < 4; ++r) {
            int m = rowA0 + wrow + mt * 16 + q * 4 + r;
            size_t offm = (size_t)m * N;
#pragma unroll
            for (int nt = 0; nt < 4; ++nt) {
                int n = ncol0 + nt * 16;
                size_t idx = offm + n;
                float c = acc[mt][nt][r];
                if (mode == 0) {
                    float v = fast_tanh(c + sg.bias[n]);
                    sg.outf[idx] = v; sg.outbf[idx] = f2bf(v);
                } else if (mode == 1) {
                    float v = sg.rsrc[idx] - fast_tanh(c);
                    sg.outbf[idx] = f2bf(v);
                    if (sg.accum) lsum += v * v;
                } else if (mode == 2) {
                    float v = sg.rsrc[idx] + 0.1f * (c - bf2f(sg.esub[idx]));
                    sg.outf[idx] = v; sg.outbf[idx] = f2bf(v);
                } else {
                    float v = 0.9f * sg.rsrc[idx] + 0.1f * c;
                    sg.outf[idx] = v; sg.outbf[idx] = f2bf(v);
                    if (sg.accum) lsum += v * v;
                }
            }
        }
    }

    if (sg.accum) {
        lsum *= 0.5f;
#pragma unroll
        for (int o = 32; o > 0; o >>= 1) lsum += __shfl_down(lsum, o);
        if (lane == 0) red[wave] = lsum;
        __syncthreads();
        if (tid == 0) atomicAdd(errAcc, red[0] + red[1] + red[2] + red[3]);
    }
}

// ---------------- host ----------------

extern "C" void kernel_launch(void* const* d_in, const int* in_sizes, int n_in,
                              void* d_out, int out_size, void* d_ws, size_t ws_size,
                              hipStream_t stream) {
    const float* x  = (const float*)d_in[0];
    const float* W0 = (const float*)d_in[1];
    const float* b0 = (const float*)d_in[2];
    const float* W1 = (const float*)d_in[3];
    const float* b1 = (const float*)d_in[4];
    const float* W2 = (const float*)d_in[5];
    const float* b2 = (const float*)d_in[6];

    const int Bz = 4096;  // batch

    char* ws = (char*)d_ws;
    size_t off = 0;
    auto alloc = [&](size_t bytes) -> char* {
        char* p = ws + off;
        off += (bytes + 255) & ~(size_t)255;
        return p;
    };

    float* r1f = (float*)alloc((size_t)Bz * 2048 * 4);
    float* r2f = (float*)alloc((size_t)Bz * 2048 * 4);
    u16*   r1b = (u16*)  alloc((size_t)Bz * 2048 * 2);
    u16*   r2b = (u16*)  alloc((size_t)Bz * 2048 * 2);
    u16*   r3b = (u16*)  alloc((size_t)Bz * 512 * 2);
    u16*   e0b = (u16*)  alloc((size_t)Bz * 1024 * 2);
    u16*   e1b = (u16*)  alloc((size_t)Bz * 2048 * 2);
    u16*   e2b = (u16*)  alloc((size_t)Bz * 2048 * 2);
    u16*   xb  = (u16*)  alloc((size_t)Bz * 1024 * 2);
    u16*   W0b = (u16*)  alloc((size_t)2048 * 1024 * 2);
    u16*   W0t = (u16*)  alloc((size_t)1024 * 2048 * 2);
    u16*   W1b = (u16*)  alloc((size_t)2048 * 2048 * 2);
    u16*   W1t = (u16*)  alloc((size_t)2048 * 2048 * 2);
    u16*   W2b = (u16*)  alloc((size_t)512 * 2048 * 2);
    u16*   W2t = (u16*)  alloc((size_t)2048 * 512 * 2);

    float* r3f    = (float*)d_out;            // 4096 x 512
    float* errAcc = ((float*)d_out) + (size_t)Bz * 512;

    cvt_bf16<<<(Bz * 1024 / 4) / 256, 256, 0, stream>>>(x,  xb,  Bz * 1024 / 4);
    cvt_bf16<<<(2048 * 1024 / 4) / 256, 256, 0, stream>>>(W0, W0b, 2048 * 1024 / 4);
    cvt_bf16<<<(2048 * 2048 / 4) / 256, 256, 0, stream>>>(W1, W1b, 2048 * 2048 / 4);
    cvt_bf16<<<(512 * 2048 / 4) / 256, 256, 0, stream>>>(W2, W2b, 512 * 2048 / 4);
    transpose_cvt<<<dim3(1024 / 32, 2048 / 32), 256, 0, stream>>>(W0, W0t, 2048, 1024);
    transpose_cvt<<<dim3(2048 / 32, 2048 / 32), 256, 0, stream>>>(W1, W1t, 2048, 2048);
    transpose_cvt<<<dim3(2048 / 32, 512 / 32),  256, 0, stream>>>(W2, W2t, 512, 2048);

    hipMemsetAsync(errAcc, 0, 4, stream);

    auto mkseg = [&](const u16* A, const u16* B, int K, int N,
                     const float* rsrc, const float* bias, const u16* esub,
                     float* outf, u16* outbf, int mode, int accum, int blkStart) {
        Seg s;
        s.A = A; s.B = B; s.rsrc = rsrc; s.bias = bias; s.esub = esub;
        s.outf = outf; s.outbf = outbf;
        s.K = K; s.N = N; s.blkStart = blkStart;
        s.mode = mode; s.accum = accum;
        return s;
    };
    auto nblk = [&](int N) { return (N / 128) * (Bz / 128); };

    auto launch1 = [&](Seg s0) {
        Phase ph;
        int b0 = nblk(s0.N);
        ph.seg[0] = s0; ph.seg[1] = s0; ph.seg[2] = s0;
        ph.bEnd0 = b0; ph.bEnd1 = b0;
        pc_phase<<<b0, 256, 0, stream>>>(ph, errAcc);
    };
    auto launch3 = [&](Seg s0, Seg s1, Seg s2) {
        Phase ph;
        int b0 = nblk(s0.N), b1 = nblk(s1.N), b2 = nblk(s2.N);
        s1.blkStart = b0; s2.blkStart = b0 + b1;
        ph.seg[0] = s0; ph.seg[1] = s1; ph.seg[2] = s2;
        ph.bEnd0 = b0; ph.bEnd1 = b0 + b1;
        pc_phase<<<b0 + b1 + b2, 256, 0, stream>>>(ph, errAcc);
    };

    // forward init (sequential dependency)
    launch1(mkseg(xb,  W0b, 1024, 2048, nullptr, b0, nullptr, r1f, r1b, 0, 0, 0));
    launch1(mkseg(r1b, W1b, 2048, 2048, nullptr, b1, nullptr, r2f, r2b, 0, 0, 0));
    launch1(mkseg(r2b, W2b, 2048, 512,  nullptr, b2, nullptr, r3f, r3b, 0, 0, 0));

    // 20 relaxation steps: fused error phase, fused update phase
    for (int s = 0; s < 20; ++s) {
        int last = (s == 19) ? 1 : 0;
        // errors (independent; descending K for schedule balance)
        launch3(mkseg(r2b, W1t, 2048, 2048, r1f, nullptr, nullptr, nullptr, e1b, 1, 0, 0),
                mkseg(r1b, W0t, 2048, 1024, x,   nullptr, nullptr, nullptr, e0b, 1, 0, 0),
                mkseg(r3b, W2t, 512,  2048, r2f, nullptr, nullptr, nullptr, e2b, 1, 0, 0));
        // updates (independent; descending K)
        launch3(mkseg(e1b, W1b, 2048, 2048, r2f, nullptr, e2b, r2f, r2b, 2, 0, 0),
                mkseg(e2b, W2b, 2048, 512,  r3f, nullptr, nullptr, r3f, r3b, 3, last, 0),
                mkseg(e0b, W0b, 1024, 2048, r1f, nullptr, e1b, r1f, r1b, 2, 0, 0));
    }

    // final errors with 0.5*sum(e^2) accumulation (r3^2 added by last UPD3)
    launch3(mkseg(r2b, W1t, 2048, 2048, r1f, nullptr, nullptr, nullptr, e1b, 1, 1, 0),
            mkseg(r1b, W0t, 2048, 1024, x,   nullptr, nullptr, nullptr, e0b, 1, 1, 0),
            mkseg(r3b, W2t, 512,  2048, r2f, nullptr, nullptr, nullptr, e2b, 1, 1, 0));
}

// Round 6
// 6445.593 us; speedup vs baseline: 1.4067x; 1.1369x over previous
//
#include <hip/hip_runtime.h>

typedef unsigned short u16;
typedef __bf16 bf16_t;
typedef bf16_t bf16x8 __attribute__((ext_vector_type(8)));
typedef u16 u16x8 __attribute__((ext_vector_type(8)));
typedef float f32x4 __attribute__((ext_vector_type(4)));

__device__ __forceinline__ u16 f2bf(float f) {
    unsigned u = __builtin_bit_cast(unsigned, f);
    u += 0x7fffu + ((u >> 16) & 1u);   // RNE
    return (u16)(u >> 16);
}
__device__ __forceinline__ float bf2f(u16 h) {
    unsigned u = ((unsigned)h) << 16;
    return __builtin_bit_cast(float, u);
}
__device__ __forceinline__ float fast_tanh(float x) {
    x = fminf(fmaxf(x, -20.f), 20.f);
    float e = __expf(2.f * x);
    return (e - 1.f) * __builtin_amdgcn_rcpf(e + 1.f);
}

__device__ __forceinline__ void gload_lds16(const void* g, void* l) {
    __builtin_amdgcn_global_load_lds((__attribute__((address_space(1))) void*)(g),
                                     (__attribute__((address_space(3))) void*)(l),
                                     16, 0, 0);
}

// ---------------- conversion kernels ----------------

__global__ void cvt_bf16(const float* __restrict__ src, u16* __restrict__ dst, int n4) {
    int i = blockIdx.x * blockDim.x + threadIdx.x;
    if (i < n4) {
        float4 v = ((const float4*)src)[i];
        ushort4 o;
        o.x = f2bf(v.x); o.y = f2bf(v.y); o.z = f2bf(v.z); o.w = f2bf(v.w);
        ((ushort4*)dst)[i] = o;
    }
}

// W: R x C fp32  ->  WT: C x R bf16
__global__ void transpose_cvt(const float* __restrict__ W, u16* __restrict__ WT, int R, int C) {
    __shared__ float tile[32][33];
    int c0 = blockIdx.x * 32, r0 = blockIdx.y * 32;
    int tx = threadIdx.x & 31, ty = threadIdx.x >> 5;  // 32x8
#pragma unroll
    for (int i = 0; i < 32; i += 8)
        tile[ty + i][tx] = W[(size_t)(r0 + ty + i) * C + (c0 + tx)];
    __syncthreads();
#pragma unroll
    for (int i = 0; i < 32; i += 8)
        WT[(size_t)(c0 + ty + i) * R + (r0 + tx)] = f2bf(tile[tx][ty + i]);
}

// ---------------- segmented fused NT GEMM phase (BK=32, register diet) ----------------
// Each segment: C[m,n] = sum_k A[m,k]*B[n,k]; A: 4096 x K (lda=K), B: N x K (ldb=K)
// mode 0 (FWD):  v = tanh(C + bias[n]);               write outf, outbf
// mode 1 (ERR):  v = rsrc - tanh(C);                  write outbf        (+ 0.5 v^2 if accum)
// mode 2 (UPD):  v = rsrc + 0.1*(C - bf2f(esub));     write outf, outbf
// mode 3 (UPD3): v = 0.9*rsrc + 0.1*C;                write outf, outbf  (+ 0.5 v^2 if accum)

struct Seg {
    const u16* A; const u16* B;
    const float* rsrc; const float* bias;
    const u16* esub;
    float* outf; u16* outbf;
    int K, N, blkStart, mode, accum;
};
struct Phase {
    Seg seg[3];
    int bEnd0, bEnd1;   // segment boundaries in linear block space
};

// __launch_bounds__(256, 4): target 4 waves/EU -> <=128 unified regs/wave ->
// 4 blocks/CU (R1-R4 were register-capped at 2 blocks/CU: ~112 VGPR + 64 AGPR)
__global__ __launch_bounds__(256, 4) void pc_phase(Phase ph, float* __restrict__ errAcc) {
    __shared__ u16 As[4096];   // [kb 0..3][row 0..127][8]
    __shared__ u16 Bs[4096];
    __shared__ float red[4];

    const int bid = blockIdx.x;
    const int segi = (bid >= ph.bEnd0 ? 1 : 0) + (bid >= ph.bEnd1 ? 1 : 0);

    const int local = bid - ph.seg[segi].blkStart;
    // weight-tile-major ordering: 32 consecutive blocks share one B (weight) tile
    const int bx = local >> 5;        // N-tile (weight rows)
    const int by = local & 31;        // M-tile (batch rows)
    const int K = ph.seg[segi].K;

    const int tid  = threadIdx.x;
    const int wave = tid >> 6, lane = tid & 63;
    const int q    = lane >> 4, ln = lane & 15;
    const int wrow = (wave >> 1) * 64, wcol = (wave & 1) * 64;

    const int rowA0 = by * 128;
    const int rowB0 = bx * 128;

    // only A, B, K live through the K-loop; epilogue params fetched after it
    const u16* gA0 = ph.seg[segi].A + (size_t)(rowA0 + lane) * K + wave * 8;
    const u16* gA1 = gA0 + (size_t)64 * K;
    const u16* gB0 = ph.seg[segi].B + (size_t)(rowB0 + lane) * K + wave * 8;
    const u16* gB1 = gB0 + (size_t)64 * K;
    u16* lA0 = &As[wave * 1024];
    u16* lA1 = &As[wave * 1024 + 512];
    u16* lB0 = &Bs[wave * 1024];
    u16* lB1 = &Bs[wave * 1024 + 512];

    f32x4 acc[4][4];
#pragma unroll
    for (int i = 0; i < 4; ++i)
#pragma unroll
        for (int j = 0; j < 4; ++j)
            acc[i][j] = (f32x4){0.f, 0.f, 0.f, 0.f};

    // fragment read base: As[q*1024 + (row)*8], row = wrow + mt*16 + ln
    // 16-row step = 16*8 = 128 u16  (R5 bug: used 256 -> read past the array)
    const u16* asrd = &As[q * 1024 + (wrow + ln) * 8];
    const u16* bsrd = &Bs[q * 1024 + (wcol + ln) * 8];

    for (int it = K >> 5; it > 0; --it) {
        gload_lds16(gA0, lA0);
        gload_lds16(gA1, lA1);
        gload_lds16(gB0, lB0);
        gload_lds16(gB1, lB1);
        gA0 += 32; gA1 += 32; gB0 += 32; gB1 += 32;
        __syncthreads();

        bf16x8 a[4], b[4];
#pragma unroll
        for (int mt = 0; mt < 4; ++mt)
            a[mt] = __builtin_bit_cast(bf16x8, *(const u16x8*)&asrd[mt * 128]);
#pragma unroll
        for (int nt = 0; nt < 4; ++nt)
            b[nt] = __builtin_bit_cast(bf16x8, *(const u16x8*)&bsrd[nt * 128]);
#pragma unroll
        for (int mt = 0; mt < 4; ++mt)
#pragma unroll
            for (int nt = 0; nt < 4; ++nt)
                acc[mt][nt] = __builtin_amdgcn_mfma_f32_16x16x32_bf16(
                    a[mt], b[nt], acc[mt][nt], 0, 0, 0);
        __syncthreads();
    }

    // epilogue: fetch remaining segment params now (not live during K-loop)
    const int N = ph.seg[segi].N;
    const int mode = ph.seg[segi].mode;
    const int accum = ph.seg[segi].accum;
    const float* rsrc = ph.seg[segi].rsrc;
    const float* bias = ph.seg[segi].bias;
    const u16* esub = ph.seg[segi].esub;
    float* outf = ph.seg[segi].outf;
    u16* outbf = ph.seg[segi].outbf;

    // C/D layout: col = lane&15 (n), row = q*4 + reg (m)
    float lsum = 0.f;
    const int ncol0 = rowB0 + wcol + ln;
#pragma unroll
    for (int mt = 0; mt < 4; ++mt) {
#pragma unroll
        for (int r = 0; r < 4; ++r) {
            int m = rowA0 + wrow + mt * 16 + q * 4 + r;
            size_t offm = (size_t)m * N;
#pragma unroll
            for (int nt = 0; nt < 4; ++nt) {
                int n = ncol0 + nt * 16;
                size_t idx = offm + n;
                float c = acc[mt][nt][r];
                if (mode == 0) {
                    float v = fast_tanh(c + bias[n]);
                    outf[idx] = v; outbf[idx] = f2bf(v);
                } else if (mode == 1) {
                    float v = rsrc[idx] - fast_tanh(c);
                    outbf[idx] = f2bf(v);
                    if (accum) lsum += v * v;
                } else if (mode == 2) {
                    float v = rsrc[idx] + 0.1f * (c - bf2f(esub[idx]));
                    outf[idx] = v; outbf[idx] = f2bf(v);
                } else {
                    float v = 0.9f * rsrc[idx] + 0.1f * c;
                    outf[idx] = v; outbf[idx] = f2bf(v);
                    if (accum) lsum += v * v;
                }
            }
        }
    }

    if (accum) {
        lsum *= 0.5f;
#pragma unroll
        for (int o = 32; o > 0; o >>= 1) lsum += __shfl_down(lsum, o);
        if (lane == 0) red[wave] = lsum;
        __syncthreads();
        if (tid == 0) atomicAdd(errAcc, red[0] + red[1] + red[2] + red[3]);
    }
}

// ---------------- host ----------------

extern "C" void kernel_launch(void* const* d_in, const int* in_sizes, int n_in,
                              void* d_out, int out_size, void* d_ws, size_t ws_size,
                              hipStream_t stream) {
    const float* x  = (const float*)d_in[0];
    const float* W0 = (const float*)d_in[1];
    const float* b0 = (const float*)d_in[2];
    const float* W1 = (const float*)d_in[3];
    const float* b1 = (const float*)d_in[4];
    const float* W2 = (const float*)d_in[5];
    const float* b2 = (const float*)d_in[6];

    const int Bz = 4096;  // batch

    char* ws = (char*)d_ws;
    size_t off = 0;
    auto alloc = [&](size_t bytes) -> char* {
        char* p = ws + off;
        off += (bytes + 255) & ~(size_t)255;
        return p;
    };

    float* r1f = (float*)alloc((size_t)Bz * 2048 * 4);
    float* r2f = (float*)alloc((size_t)Bz * 2048 * 4);
    u16*   r1b = (u16*)  alloc((size_t)Bz * 2048 * 2);
    u16*   r2b = (u16*)  alloc((size_t)Bz * 2048 * 2);
    u16*   r3b = (u16*)  alloc((size_t)Bz * 512 * 2);
    u16*   e0b = (u16*)  alloc((size_t)Bz * 1024 * 2);
    u16*   e1b = (u16*)  alloc((size_t)Bz * 2048 * 2);
    u16*   e2b = (u16*)  alloc((size_t)Bz * 2048 * 2);
    u16*   xb  = (u16*)  alloc((size_t)Bz * 1024 * 2);
    u16*   W0b = (u16*)  alloc((size_t)2048 * 1024 * 2);
    u16*   W0t = (u16*)  alloc((size_t)1024 * 2048 * 2);
    u16*   W1b = (u16*)  alloc((size_t)2048 * 2048 * 2);
    u16*   W1t = (u16*)  alloc((size_t)2048 * 2048 * 2);
    u16*   W2b = (u16*)  alloc((size_t)512 * 2048 * 2);
    u16*   W2t = (u16*)  alloc((size_t)2048 * 512 * 2);

    float* r3f    = (float*)d_out;            // 4096 x 512
    float* errAcc = ((float*)d_out) + (size_t)Bz * 512;

    cvt_bf16<<<(Bz * 1024 / 4) / 256, 256, 0, stream>>>(x,  xb,  Bz * 1024 / 4);
    cvt_bf16<<<(2048 * 1024 / 4) / 256, 256, 0, stream>>>(W0, W0b, 2048 * 1024 / 4);
    cvt_bf16<<<(2048 * 2048 / 4) / 256, 256, 0, stream>>>(W1, W1b, 2048 * 2048 / 4);
    cvt_bf16<<<(512 * 2048 / 4) / 256, 256, 0, stream>>>(W2, W2b, 512 * 2048 / 4);
    transpose_cvt<<<dim3(1024 / 32, 2048 / 32), 256, 0, stream>>>(W0, W0t, 2048, 1024);
    transpose_cvt<<<dim3(2048 / 32, 2048 / 32), 256, 0, stream>>>(W1, W1t, 2048, 2048);
    transpose_cvt<<<dim3(2048 / 32, 512 / 32),  256, 0, stream>>>(W2, W2t, 512, 2048);

    hipMemsetAsync(errAcc, 0, 4, stream);

    auto mkseg = [&](const u16* A, const u16* B, int K, int N,
                     const float* rsrc, const float* bias, const u16* esub,
                     float* outf, u16* outbf, int mode, int accum, int blkStart) {
        Seg s;
        s.A = A; s.B = B; s.rsrc = rsrc; s.bias = bias; s.esub = esub;
        s.outf = outf; s.outbf = outbf;
        s.K = K; s.N = N; s.blkStart = blkStart;
        s.mode = mode; s.accum = accum;
        return s;
    };
    auto nblk = [&](int N) { return (N / 128) * (Bz / 128); };

    auto launch1 = [&](Seg s0) {
        Phase ph;
        int b0 = nblk(s0.N);
        ph.seg[0] = s0; ph.seg[1] = s0; ph.seg[2] = s0;
        ph.bEnd0 = b0; ph.bEnd1 = b0;
        pc_phase<<<b0, 256, 0, stream>>>(ph, errAcc);
    };
    auto launch3 = [&](Seg s0, Seg s1, Seg s2) {
        Phase ph;
        int b0 = nblk(s0.N), b1 = nblk(s1.N), b2 = nblk(s2.N);
        s1.blkStart = b0; s2.blkStart = b0 + b1;
        ph.seg[0] = s0; ph.seg[1] = s1; ph.seg[2] = s2;
        ph.bEnd0 = b0; ph.bEnd1 = b0 + b1;
        pc_phase<<<b0 + b1 + b2, 256, 0, stream>>>(ph, errAcc);
    };

    // forward init (sequential dependency)
    launch1(mkseg(xb,  W0b, 1024, 2048, nullptr, b0, nullptr, r1f, r1b, 0, 0, 0));
    launch1(mkseg(r1b, W1b, 2048, 2048, nullptr, b1, nullptr, r2f, r2b, 0, 0, 0));
    launch1(mkseg(r2b, W2b, 2048, 512,  nullptr, b2, nullptr, r3f, r3b, 0, 0, 0));

    // 20 relaxation steps: fused error phase, fused update phase
    for (int s = 0; s < 20; ++s) {
        int last = (s == 19) ? 1 : 0;
        // errors (independent)
        launch3(mkseg(r2b, W1t, 2048, 2048, r1f, nullptr, nullptr, nullptr, e1b, 1, 0, 0),
                mkseg(r1b, W0t, 2048, 1024, x,   nullptr, nullptr, nullptr, e0b, 1, 0, 0),
                mkseg(r3b, W2t, 512,  2048, r2f, nullptr, nullptr, nullptr, e2b, 1, 0, 0));
        // updates (independent)
        launch3(mkseg(e1b, W1b, 2048, 2048, r2f, nullptr, e2b, r2f, r2b, 2, 0, 0),
                mkseg(e2b, W2b, 2048, 512,  r3f, nullptr, nullptr, r3f, r3b, 3, last, 0),
                mkseg(e0b, W0b, 1024, 2048, r1f, nullptr, e1b, r1f, r1b, 2, 0, 0));
    }

    // final errors with 0.5*sum(e^2) accumulation (r3^2 added by last UPD3)
    launch3(mkseg(r2b, W1t, 2048, 2048, r1f, nullptr, nullptr, nullptr, e1b, 1, 1, 0),
            mkseg(r1b, W0t, 2048, 1024, x,   nullptr, nullptr, nullptr, e0b, 1, 1, 0),
            mkseg(r3b, W2t, 512,  2048, r2f, nullptr, nullptr, nullptr, e2b, 1, 1, 0));
}